// Round 4
// baseline (275.982 us; speedup 1.0000x reference)
//
#include <hip/hip_runtime.h>
#include <math.h>

// Qnet: per-row tiny MLP + gumbel-sigmoid straight-through gates + 5 tiny experts.
// Memory-bound: ~436 MB traffic -> ~69us floor at 6.3 TB/s.
// One thread handles 4 rows so ALL global traffic is float4-aligned.
//
// Numerics (rounds 0-3 lesson): graded vs a NUMPY FLOAT32 reference.
// Evidence: f64 refinement reduced error 3.73 -> 0.902, then three different
// f64 schemes left a BIT-IDENTICAL 0.902 flip — one gate where np-f32
// disagrees with the true f64 sign. Mechanism: in f32,
//   soft = 1/(1+expf(-z)) == 0.5 exactly for -z <= log(1+3*2^-24) ~ 1.79e-7
// (expf rounds to 1.0f, or to 1+2^-23 whose 1+e rounds to 2.0 ties-to-even),
// so np-f32 says hard=1 for z in (-1.79e-7, 0) while sign(z) says 0.
// => decision authority near the boundary is a correctly-rounded f32
// SIMULATION of the numpy forward: fmaf matmul chains (bias last),
// (float)log/tanh/exp((double)x) as CR f32 transcendentals, exact f32 op
// order, and the literal soft/den/compare chain (reproduces the dead band).
// Fast f32 path decides only when |z| >= 1e-4 (impl-to-impl z spread <~6e-6,
// no 1/t amplification between f32 impls since fl(u+1e-8f) is identical).

constexpr float EPSF = 1e-8f;

__global__ __launch_bounds__(256) void qnet_kernel(
    const float* __restrict__ x,
    const float* __restrict__ u1,
    const float* __restrict__ u2,
    const float* __restrict__ fc1_w,    // [4][4]
    const float* __restrict__ fc1_b,    // [4]
    const float* __restrict__ picker_w, // [5][4]
    const float* __restrict__ picker_b, // [5]
    const float* __restrict__ ew1,      // [5][4][4]  e,k,h
    const float* __restrict__ eb1,      // [5][4]
    const float* __restrict__ ew2,      // [5][2][4]  e,o,k
    const float* __restrict__ eb2,      // [5][2]
    float* __restrict__ out_o,          // [B][2]
    float* __restrict__ hard_o,         // [B][5]
    float* __restrict__ soft_o)         // [B][5]
{
    __shared__ float s_fc1w[16];
    __shared__ float s_fc1b[4];
    __shared__ float s_pw[20];
    __shared__ float s_pb[5];
    __shared__ float s_ew1[80];
    __shared__ float s_eb1[20];
    __shared__ float s_ew2[40];
    __shared__ float s_eb2[10];
    {
        const int tid = threadIdx.x;
        if (tid < 16) s_fc1w[tid] = fc1_w[tid];
        if (tid < 4)  s_fc1b[tid] = fc1_b[tid];
        if (tid < 20) s_pw[tid]   = picker_w[tid];
        if (tid < 5)  s_pb[tid]   = picker_b[tid];
        if (tid < 80) s_ew1[tid]  = ew1[tid];
        if (tid < 20) s_eb1[tid]  = eb1[tid];
        if (tid < 40) s_ew2[tid]  = ew2[tid];
        if (tid < 10) s_eb2[tid]  = eb2[tid];
    }
    __syncthreads();

    const long long t = (long long)blockIdx.x * blockDim.x + threadIdx.x; // rows 4t..4t+3

    const float4* x4  = reinterpret_cast<const float4*>(x);
    const float4* u14 = reinterpret_cast<const float4*>(u1);
    const float4* u24 = reinterpret_cast<const float4*>(u2);

    float xr[4][4];
#pragma unroll
    for (int r = 0; r < 4; ++r) {
        float4 v = x4[4 * t + r];
        xr[r][0] = v.x; xr[r][1] = v.y; xr[r][2] = v.z; xr[r][3] = v.w;
    }
    float u1f[20], u2f[20];
#pragma unroll
    for (int k = 0; k < 5; ++k) {
        float4 a = u14[5 * t + k];
        u1f[4 * k + 0] = a.x; u1f[4 * k + 1] = a.y; u1f[4 * k + 2] = a.z; u1f[4 * k + 3] = a.w;
        float4 b = u24[5 * t + k];
        u2f[4 * k + 0] = b.x; u2f[4 * k + 1] = b.y; u2f[4 * k + 2] = b.z; u2f[4 * k + 3] = b.w;
    }

    float softf[20], hardf[20], outf[8];

#pragma unroll
    for (int r = 0; r < 4; ++r) {
        // fast-path h = tanh(fc1(x))
        float h[4];
#pragma unroll
        for (int j = 0; j < 4; ++j) {
            float a = s_fc1b[j];
#pragma unroll
            for (int i = 0; i < 4; ++i) a += xr[r][i] * s_fc1w[4 * j + i];
            h[j] = tanhf(a);
        }

        float o0 = 0.0f, o1 = 0.0f;
#pragma unroll
        for (int c = 0; c < 5; ++c) {
            // picker logit (fast path)
            float lg = s_pb[c];
#pragma unroll
            for (int j = 0; j < 4; ++j) lg += h[j] * s_pw[4 * c + j];

            const float uu1 = u1f[5 * r + c];
            const float uu2 = u2f[5 * r + c];
            const float g1 = -logf(-logf(uu1 + EPSF) + EPSF);
            const float g2 = -logf(-logf(uu2 + EPSF) + EPSF);
            const float z = lg + (g1 - g2);

            float sft, hrd;
            if (__builtin_expect(fabsf(z) < 1e-4f, 0)) {
                // ---- CR-f32 simulation of the numpy float32 forward ----
                // h: fmaf chain over i (matmul), bias added AFTER, CR tanh32
                float h32[4];
#pragma unroll
                for (int j = 0; j < 4; ++j) {
                    float acc = 0.0f;
#pragma unroll
                    for (int i = 0; i < 4; ++i)
                        acc = fmaf(xr[r][i], s_fc1w[4 * j + i], acc);
                    const float hpre = acc + s_fc1b[j];
                    h32[j] = (float)tanh((double)hpre);
                }
                // logits: fmaf chain over j, bias after
                float lacc = 0.0f;
#pragma unroll
                for (int j = 0; j < 4; ++j)
                    lacc = fmaf(h32[j], s_pw[4 * c + j], lacc);
                const float lg32 = lacc + s_pb[c];
                // gumbel chain, every numpy op rounded to f32, CR log32
                const float a1 = uu1 + EPSF;
                const float l1 = (float)log((double)a1);
                const float b1 = (-l1) + EPSF;
                const float g1s = -((float)log((double)b1));
                const float a2 = uu2 + EPSF;
                const float l2 = (float)log((double)a2);
                const float b2 = (-l2) + EPSF;
                const float g2s = -((float)log((double)b2));
                const float dd = g1s - g2s;          // f32, matches logits + (g1-g2)
                const float z32 = lg32 + dd;
                // sigmoid EXACTLY as np-f32: e = exp32(-z); soft = 1/(1+e)
                const float e32 = (float)exp((double)(-z32));  // CR exp32
                const float den = 1.0f + e32;                  // f32 add (ties-to-even)
                const float s32 = 1.0f / den;                  // f32 IEEE divide
                sft = s32;
                hrd = (s32 >= 0.5f) ? 1.0f : 0.0f;             // reproduces dead band
            } else {
                sft = 1.0f / (1.0f + expf(-z));
                hrd = (z >= 0.0f) ? 1.0f : 0.0f;
            }
            softf[5 * r + c] = sft;
            hardf[5 * r + c] = hrd;

            // expert c: Linear(4,4)->ReLU->Linear(4,2)
            float eh[4];
#pragma unroll
            for (int k = 0; k < 4; ++k) {
                float a = s_eb1[4 * c + k];
#pragma unroll
                for (int j = 0; j < 4; ++j) a += h[j] * s_ew1[16 * c + 4 * k + j];
                eh[k] = fmaxf(a, 0.0f);
            }
            float e0 = s_eb2[2 * c + 0];
            float e1 = s_eb2[2 * c + 1];
#pragma unroll
            for (int k = 0; k < 4; ++k) {
                e0 += eh[k] * s_ew2[8 * c + 0 + k];
                e1 += eh[k] * s_ew2[8 * c + 4 + k];
            }
            o0 += hrd * e0;
            o1 += hrd * e1;
        }
        outf[2 * r + 0] = o0;
        outf[2 * r + 1] = o1;
    }

    float4* out4  = reinterpret_cast<float4*>(out_o);
    float4* hard4 = reinterpret_cast<float4*>(hard_o);
    float4* soft4 = reinterpret_cast<float4*>(soft_o);
    out4[2 * t + 0] = make_float4(outf[0], outf[1], outf[2], outf[3]);
    out4[2 * t + 1] = make_float4(outf[4], outf[5], outf[6], outf[7]);
#pragma unroll
    for (int k = 0; k < 5; ++k) {
        hard4[5 * t + k] = make_float4(hardf[4 * k + 0], hardf[4 * k + 1], hardf[4 * k + 2], hardf[4 * k + 3]);
        soft4[5 * t + k] = make_float4(softf[4 * k + 0], softf[4 * k + 1], softf[4 * k + 2], softf[4 * k + 3]);
    }
}

extern "C" void kernel_launch(void* const* d_in, const int* in_sizes, int n_in,
                              void* d_out, int out_size, void* d_ws, size_t ws_size,
                              hipStream_t stream) {
    const float* x        = (const float*)d_in[0];
    const float* u1       = (const float*)d_in[1];
    const float* u2       = (const float*)d_in[2];
    const float* fc1_w    = (const float*)d_in[3];
    const float* fc1_b    = (const float*)d_in[4];
    const float* picker_w = (const float*)d_in[5];
    const float* picker_b = (const float*)d_in[6];
    const float* ew1      = (const float*)d_in[7];
    const float* eb1      = (const float*)d_in[8];
    const float* ew2      = (const float*)d_in[9];
    const float* eb2      = (const float*)d_in[10];

    const long long B = in_sizes[0] / 4;        // rows
    float* out  = (float*)d_out;                // [B][2]
    float* hard = out + (size_t)B * 2;          // [B][5]
    float* soft = hard + (size_t)B * 5;         // [B][5]

    const int threads = 256;
    const long long nthreads = B / 4;           // 4 rows per thread
    const int blocks = (int)((nthreads + threads - 1) / threads);

    qnet_kernel<<<blocks, threads, 0, stream>>>(
        x, u1, u2, fc1_w, fc1_b, picker_w, picker_b,
        ew1, eb1, ew2, eb2, out, hard, soft);
}

// Round 5
// 150.139 us; speedup vs baseline: 1.8382x; 1.8382x over previous
//
#include <hip/hip_runtime.h>
#include <math.h>

// Qnet: per-row tiny MLP + gumbel-sigmoid straight-through gates + 5 tiny experts.
//
// Round-4 post-mortem: PASSED at 348us but VGPR=244 / occupancy 9.8% — the
// inlined f64 CR path bloated regalloc of the whole kernel. This round splits:
//   Kernel A (hot, lean): 1 row/thread, fast __logf/__expf math, flags gates
//     with |z| < 1e-4 into a d_ws list (expected ~1e3 of 21M).
//   Kernel B (rare patch): bit-exact copy of the round-4 CR-f32 numpy
//     simulation for flagged gates; fixes hard/soft and atomically patches out.
// Fast-path safety: v_log_f32 has bounded RELATIVE error, so
// g = -log(t+eps) has bounded ABSOLUTE error (~2.4e-7) even as u->1;
// total fast-z error ~1e-6 << 1e-4 flag window. Decisions outside the
// window agree with np-f32; inside, kernel B is the authority.

constexpr float EPSF = 1e-8f;

__device__ __forceinline__ float fast_tanh(float a) {
    const float ea = __expf(-2.0f * fabsf(a));
    const float r = (1.0f - ea) * __builtin_amdgcn_rcpf(1.0f + ea);
    return copysignf(r, a);
}

__global__ __launch_bounds__(256) void qnet_main(
    const float* __restrict__ x,
    const float* __restrict__ u1,
    const float* __restrict__ u2,
    const float* __restrict__ fc1_w,    // [4][4]
    const float* __restrict__ fc1_b,    // [4]
    const float* __restrict__ picker_w, // [5][4]
    const float* __restrict__ picker_b, // [5]
    const float* __restrict__ ew1,      // [5][4][4]
    const float* __restrict__ eb1,      // [5][4]
    const float* __restrict__ ew2,      // [5][2][4]
    const float* __restrict__ eb2,      // [5][2]
    float* __restrict__ out_o,          // [B][2]
    float* __restrict__ hard_o,         // [B][5]
    float* __restrict__ soft_o,         // [B][5]
    unsigned* __restrict__ flag_cnt,    // d_ws[0]
    unsigned* __restrict__ flag_list,   // d_ws[1..]
    unsigned flag_cap)
{
    __shared__ float s_fc1w[16];
    __shared__ float s_fc1b[4];
    __shared__ float s_pw[20];
    __shared__ float s_pb[5];
    __shared__ float s_ew1[80];
    __shared__ float s_eb1[20];
    __shared__ float s_ew2[40];
    __shared__ float s_eb2[10];
    {
        const int tid = threadIdx.x;
        if (tid < 16) s_fc1w[tid] = fc1_w[tid];
        if (tid < 4)  s_fc1b[tid] = fc1_b[tid];
        if (tid < 20) s_pw[tid]   = picker_w[tid];
        if (tid < 5)  s_pb[tid]   = picker_b[tid];
        if (tid < 80) s_ew1[tid]  = ew1[tid];
        if (tid < 20) s_eb1[tid]  = eb1[tid];
        if (tid < 40) s_ew2[tid]  = ew2[tid];
        if (tid < 10) s_eb2[tid]  = eb2[tid];
    }
    __syncthreads();

    const unsigned row = blockIdx.x * blockDim.x + threadIdx.x;

    const float4 xv = reinterpret_cast<const float4*>(x)[row];
    const float xr[4] = {xv.x, xv.y, xv.z, xv.w};

    float h[4];
#pragma unroll
    for (int j = 0; j < 4; ++j) {
        float a = s_fc1b[j];
#pragma unroll
        for (int i = 0; i < 4; ++i) a += xr[i] * s_fc1w[4 * j + i];
        h[j] = fast_tanh(a);
    }

    float o0 = 0.0f, o1 = 0.0f;
#pragma unroll
    for (int c = 0; c < 5; ++c) {
        float lg = s_pb[c];
#pragma unroll
        for (int j = 0; j < 4; ++j) lg += h[j] * s_pw[4 * c + j];

        const float uu1 = u1[5u * row + c];
        const float uu2 = u2[5u * row + c];
        const float t1 = -__logf(uu1 + EPSF);   // > 0 (u < 1)
        const float t2 = -__logf(uu2 + EPSF);
        const float g1 = -__logf(t1 + EPSF);
        const float g2 = -__logf(t2 + EPSF);
        const float z = lg + (g1 - g2);

        const float sft = __builtin_amdgcn_rcpf(1.0f + __expf(-z));
        const float hrd = (z >= 0.0f) ? 1.0f : 0.0f;

        if (__builtin_expect(fabsf(z) < 1e-4f, 0)) {
            const unsigned slot = atomicAdd(flag_cnt, 1u);
            if (slot < flag_cap)
                flag_list[slot] = ((5u * row + c) << 1) | (z >= 0.0f ? 1u : 0u);
        }

        soft_o[5u * row + c] = sft;
        hard_o[5u * row + c] = hrd;

        float eh[4];
#pragma unroll
        for (int k = 0; k < 4; ++k) {
            float a = s_eb1[4 * c + k];
#pragma unroll
            for (int j = 0; j < 4; ++j) a += h[j] * s_ew1[16 * c + 4 * k + j];
            eh[k] = fmaxf(a, 0.0f);
        }
        float e0 = s_eb2[2 * c + 0];
        float e1 = s_eb2[2 * c + 1];
#pragma unroll
        for (int k = 0; k < 4; ++k) {
            e0 += eh[k] * s_ew2[8 * c + 0 + k];
            e1 += eh[k] * s_ew2[8 * c + 4 + k];
        }
        o0 += hrd * e0;
        o1 += hrd * e1;
    }

    reinterpret_cast<float2*>(out_o)[row] = make_float2(o0, o1);
}

// ---- rare patch kernel: bit-exact round-4 CR-f32 numpy simulation ----
__global__ __launch_bounds__(256) void qnet_patch(
    const float* __restrict__ x,
    const float* __restrict__ u1,
    const float* __restrict__ u2,
    const float* __restrict__ fc1_w,
    const float* __restrict__ fc1_b,
    const float* __restrict__ picker_w,
    const float* __restrict__ picker_b,
    const float* __restrict__ ew1,
    const float* __restrict__ eb1,
    const float* __restrict__ ew2,
    const float* __restrict__ eb2,
    float* __restrict__ out_o,
    float* __restrict__ hard_o,
    float* __restrict__ soft_o,
    const unsigned* __restrict__ flag_cnt,
    const unsigned* __restrict__ flag_list,
    unsigned flag_cap)
{
    const unsigned n = min(flag_cnt[0], flag_cap);
    const unsigned stride = gridDim.x * blockDim.x;
    for (unsigned i = blockIdx.x * blockDim.x + threadIdx.x; i < n; i += stride) {
        const unsigned e = flag_list[i];
        const float fasthard = (e & 1u) ? 1.0f : 0.0f;
        const unsigned idx5 = e >> 1;
        const unsigned row = idx5 / 5u;
        const unsigned c = idx5 % 5u;

        const float4 xv = reinterpret_cast<const float4*>(x)[row];
        const float xr[4] = {xv.x, xv.y, xv.z, xv.w};
        const float uu1 = u1[idx5];
        const float uu2 = u2[idx5];

        // h: fmaf chain (matmul), bias AFTER, CR tanh32
        float h32[4];
#pragma unroll
        for (int j = 0; j < 4; ++j) {
            float acc = 0.0f;
#pragma unroll
            for (int i2 = 0; i2 < 4; ++i2)
                acc = fmaf(xr[i2], fc1_w[4 * j + i2], acc);
            const float hpre = acc + fc1_b[j];
            h32[j] = (float)tanh((double)hpre);
        }
        // logits: fmaf chain, bias after
        float lacc = 0.0f;
#pragma unroll
        for (int j = 0; j < 4; ++j)
            lacc = fmaf(h32[j], picker_w[4 * c + j], lacc);
        const float lg32 = lacc + picker_b[c];
        // gumbel chain, every numpy op rounded to f32, CR log32
        const float a1 = uu1 + EPSF;
        const float l1 = (float)log((double)a1);
        const float b1 = (-l1) + EPSF;
        const float g1s = -((float)log((double)b1));
        const float a2 = uu2 + EPSF;
        const float l2 = (float)log((double)a2);
        const float b2 = (-l2) + EPSF;
        const float g2s = -((float)log((double)b2));
        const float dd = g1s - g2s;
        const float z32 = lg32 + dd;
        // sigmoid EXACTLY as np-f32: e = exp32(-z); soft = 1/(1+e)
        const float e32 = (float)exp((double)(-z32));
        const float den = 1.0f + e32;
        const float s32 = 1.0f / den;
        const float crhard = (s32 >= 0.5f) ? 1.0f : 0.0f;

        soft_o[idx5] = s32;
        hard_o[idx5] = crhard;

        if (crhard != fasthard) {
            float eh[4];
#pragma unroll
            for (int k = 0; k < 4; ++k) {
                float a = eb1[4 * c + k];
#pragma unroll
                for (int j = 0; j < 4; ++j) a += h32[j] * ew1[16 * c + 4 * k + j];
                eh[k] = fmaxf(a, 0.0f);
            }
            float e0 = eb2[2 * c + 0];
            float e1 = eb2[2 * c + 1];
#pragma unroll
            for (int k = 0; k < 4; ++k) {
                e0 += eh[k] * ew2[8 * c + 0 + k];
                e1 += eh[k] * ew2[8 * c + 4 + k];
            }
            const float d = crhard - fasthard;   // +1 or -1
            atomicAdd(&out_o[2u * row + 0], d * e0);
            atomicAdd(&out_o[2u * row + 1], d * e1);
        }
    }
}

extern "C" void kernel_launch(void* const* d_in, const int* in_sizes, int n_in,
                              void* d_out, int out_size, void* d_ws, size_t ws_size,
                              hipStream_t stream) {
    const float* x        = (const float*)d_in[0];
    const float* u1       = (const float*)d_in[1];
    const float* u2       = (const float*)d_in[2];
    const float* fc1_w    = (const float*)d_in[3];
    const float* fc1_b    = (const float*)d_in[4];
    const float* picker_w = (const float*)d_in[5];
    const float* picker_b = (const float*)d_in[6];
    const float* ew1      = (const float*)d_in[7];
    const float* eb1      = (const float*)d_in[8];
    const float* ew2      = (const float*)d_in[9];
    const float* eb2      = (const float*)d_in[10];

    const long long B = in_sizes[0] / 4;        // rows
    float* out  = (float*)d_out;                // [B][2]
    float* hard = out + (size_t)B * 2;          // [B][5]
    float* soft = hard + (size_t)B * 5;         // [B][5]

    unsigned* flag_cnt  = (unsigned*)d_ws;
    unsigned* flag_list = flag_cnt + 1;
    const unsigned flag_cap = (unsigned)(ws_size / 4 - 1);

    hipMemsetAsync(d_ws, 0, 4, stream);         // zero the counter (capturable)

    const int threads = 256;
    const int blocks = (int)((B + threads - 1) / threads);
    qnet_main<<<blocks, threads, 0, stream>>>(
        x, u1, u2, fc1_w, fc1_b, picker_w, picker_b,
        ew1, eb1, ew2, eb2, out, hard, soft,
        flag_cnt, flag_list, flag_cap);

    qnet_patch<<<128, 256, 0, stream>>>(
        x, u1, u2, fc1_w, fc1_b, picker_w, picker_b,
        ew1, eb1, ew2, eb2, out, hard, soft,
        flag_cnt, flag_list, flag_cap);
}